// Round 4
// baseline (260.338 us; speedup 1.0000x reference)
//
#include <hip/hip_runtime.h>
#include <hip/hip_bf16.h>

// B=64, S=512, E=256, D=512
#define EDIM 256
#define SDIM 512
#define BDIM 64
#define DDIM 512
#define SPAD 514   // padded S rows per batch in Xp (2 zero rows at front)

// ws byte offsets
#define OFF_XP    0u           // bf16 [64][514][256]  = 16,842,752 B
#define OFF_GINTB 16842752u    // bf16 [512][1536]     =  1,572,864 B
#define OFF_W1B   18415616u    // bf16 [512][256]      =    262,144 B
#define OFF_CORR  18677760u    // f32  [64][2][512]    =    262,144 B
#define OFF_BI    18939904u    // f32  [512]

// prep grid partition
#define CVT_BLOCKS  4112       // 64*514*32 / 256
#define WB_BASE     4112       // + 512 weight blocks
#define CORR_BASE   4624       // + 512 corr blocks
#define PREP_BLOCKS 5136

typedef __attribute__((ext_vector_type(8))) __bf16 bf16x8;
typedef __attribute__((ext_vector_type(4))) float  f32x4;
typedef __attribute__((ext_vector_type(8))) unsigned short ushort8v;

__device__ __forceinline__ unsigned short f2bf(float f) {
    unsigned int u = __float_as_uint(f);
    u = (u + 0x7fffu + ((u >> 16) & 1u)) >> 16;   // RNE
    return (unsigned short)u;
}

// ============ launch 1: cvt_pad + weight-combine + edge-correction ============
__global__ __launch_bounds__(256) void prep_all(
    const float* __restrict__ X,
    const float* __restrict__ W1, const float* __restrict__ b1,
    const float* __restrict__ W2, const float* __restrict__ b2,
    const float* __restrict__ W3, const float* __restrict__ b3,
    const float* __restrict__ W4, const float* __restrict__ b4,
    char* __restrict__ wsb)
{
    const int tid = threadIdx.x;

    if (blockIdx.x < CVT_BLOCKS) {
        // ---- bf16 copy of X with 2 zero rows prepended per batch, 8 elem/thread ----
        unsigned short* Xp = (unsigned short*)(wsb + OFF_XP);
        const int i   = blockIdx.x * 256 + tid;    // [0, 64*514*32)
        const int row = i >> 5;                    // b*514 + j
        const int q   = i & 31;                    // 8-elem group
        const int b   = row / SPAD;
        const int j   = row - b * SPAD;
        ushort8v v;
        if (j < 2) {
            v = (ushort8v)0;
        } else {
            const float* src = X + ((size_t)(b * SDIM + j - 2)) * EDIM + q * 8;
            const float4 f0 = *(const float4*)(src);
            const float4 f1 = *(const float4*)(src + 4);
            v[0] = f2bf(f0.x); v[1] = f2bf(f0.y); v[2] = f2bf(f0.z); v[3] = f2bf(f0.w);
            v[4] = f2bf(f1.x); v[5] = f2bf(f1.y); v[6] = f2bf(f1.z); v[7] = f2bf(f1.w);
        }
        *(ushort8v*)(Xp + (size_t)row * EDIM + q * 8) = v;
        return;
    }

    if (blockIdx.x < CORR_BASE) {
        // ---- combined interior weights (delta grouping; see R0 derivation) ----
        const int d = blockIdx.x - WB_BASE;  // 0..511
        const int e = tid;                   // 0..255
        const int de = d * EDIM + e;

        const float w1  = W1[de];
        const float w20 = W2[de * 2 + 0], w21 = W2[de * 2 + 1];
        const float w30 = W3[de * 3 + 0], w31 = W3[de * 3 + 1], w32 = W3[de * 3 + 2];
        const float w40 = W4[de * 4 + 0], w41 = W4[de * 4 + 1], w42 = W4[de * 4 + 2], w43 = W4[de * 4 + 3];

        unsigned short* Gi = (unsigned short*)(wsb + OFF_GINTB) + (size_t)d * 1536;
        Gi[0 * EDIM + e] = f2bf(w40);
        Gi[1 * EDIM + e] = f2bf(w30 + w40 + w41);
        Gi[2 * EDIM + e] = f2bf(w1 + w20 + w30 + w31 + w40 + w41 + w42);
        Gi[3 * EDIM + e] = f2bf(w21 + w31 + w32 + w41 + w42 + w43);
        Gi[4 * EDIM + e] = f2bf(w32 + w42 + w43);
        Gi[5 * EDIM + e] = f2bf(w43);

        ((unsigned short*)(wsb + OFF_W1B))[de] = f2bf(w1);

        if (e == 0)
            ((float*)(wsb + OFF_BI))[d] = b1[d] + b2[d] + 2.0f * b3[d] + 3.0f * b4[d];
        return;
    }

    // ---- edge correction: interior-weights GEMM over padded x differs from the
    //      true s=0,1 rows by a rank-3 term over x[b,0..2,:] (tap-verified):
    //      corr0 = -sum_e[x0*(w31+w41+w42) + x1*(w32+w42+w43) + x2*w43] - (b3+2b4)
    //      corr1 = -sum_e[x0*w41 + x1*w42 + x2*w43] - b4
    {
        __shared__ float xs[768];
        __shared__ float pa[2][4][64];
        const int cb = blockIdx.x - CORR_BASE;   // [0,512)
        const int b  = cb >> 3;
        const int dg = (cb & 7) * 64;

        for (int i = tid; i < 768; i += 256)
            xs[i] = X[(size_t)b * (SDIM * EDIM) + i];
        __syncthreads();

        const int dl = tid & 63, eq = tid >> 6;
        const int d  = dg + dl;
        const float* w3 = W3 + (size_t)d * 768;
        const float* w4 = W4 + (size_t)d * 1024;

        float a0 = 0.f, a1 = 0.f;
        for (int e = eq * 64; e < eq * 64 + 64; ++e) {
            const float w31 = w3[3 * e + 1], w32 = w3[3 * e + 2];
            const float w41 = w4[4 * e + 1], w42 = w4[4 * e + 2], w43 = w4[4 * e + 3];
            const float x0 = xs[e], x1 = xs[256 + e], x2 = xs[512 + e];
            a0 += x0 * (w31 + w41 + w42) + x1 * (w32 + w42 + w43) + x2 * w43;
            a1 += x0 * w41 + x1 * w42 + x2 * w43;
        }
        pa[0][eq][dl] = a0;
        pa[1][eq][dl] = a1;
        __syncthreads();

        if (tid < 128) {
            const int s = tid >> 6, d2l = tid & 63, d2 = dg + d2l;
            const float v = pa[s][0][d2l] + pa[s][1][d2l] + pa[s][2][d2l] + pa[s][3][d2l];
            const float bc = (s == 0) ? (b3[d2] + 2.f * b4[d2]) : b4[d2];
            ((float*)(wsb + OFF_CORR))[((size_t)b * 2 + s) * DDIM + d2] = -v - bc;
        }
    }
}

// ============ launch 2: uniform GEMM grid ============
// blocks [0,512):    interior GEMM, s in [0,256), K=1536, + corr on s=0,1
// blocks [512,1024): tail GEMM,     s in [256,512), K=256
// LDS fragment layout uses XOR swizzle sw(r)=(r&3)^((r>>2)&3) on the 16B atom
// index (applied identically at staging-fetch and fragment-read) -> 2-way banks.
__global__ __launch_bounds__(256) void mega(
    const unsigned short* __restrict__ Xp,
    const char* __restrict__ wsb,
    const float* __restrict__ b1,
    float* __restrict__ out)
{
    __shared__ __align__(16) char smem[16384];
    const int id  = blockIdx.x;
    const int tid = threadIdx.x;

    const bool is_tail = id >= 512;
    const int  idx  = is_tail ? id - 512 : id;
    const int  row0 = (idx & 127) * 128;
    const int  col0 = (idx >> 7) * 128;
    const int  K     = is_tail ? 256 : 1536;
    const int  s_lo  = is_tail ? 256 : 0;
    const int  aoff  = is_tail ? 2 : 0;
    const unsigned short* Gbf = is_tail ? (const unsigned short*)(wsb + OFF_W1B)
                                        : (const unsigned short*)(wsb + OFF_GINTB);
    const float* bias = is_tail ? b1 : (const float*)(wsb + OFF_BI);

    unsigned short* Alds = (unsigned short*)smem;             // [128][32]
    unsigned short* Blds = (unsigned short*)(smem + 8192);    // [128][32]

    const int w = tid >> 6;
    const int l = tid & 63;

    // staging: wave w stages chunks {2w,2w+1} of A and B (16 rows x 64 B each)
    const int sub = l >> 2;
    const int kb  = (((l & 3) ^ ((sub & 3) ^ ((sub >> 2) & 3)))) * 16;  // swizzled atom

    const int ra0 = row0 + 32 * w + sub;
    const int ra1 = ra0 + 16;
    const int ba0 = ra0 >> 8, sa0 = ra0 & 255;
    const int ba1 = ra1 >> 8, sa1 = ra1 & 255;
    const char* ga0 = (const char*)(Xp + ((size_t)(ba0 * SPAD + s_lo + sa0 + aoff)) * EDIM) + kb;
    const char* ga1 = (const char*)(Xp + ((size_t)(ba1 * SPAD + s_lo + sa1 + aoff)) * EDIM) + kb;
    const char* gb0 = (const char*)(Gbf + (size_t)(col0 + 32 * w + sub) * K) + kb;
    const char* gb1 = (const char*)(Gbf + (size_t)(col0 + 32 * w + 16 + sub) * K) + kb;

    unsigned short* la0 = Alds + (32 * w) * 32;
    unsigned short* la1 = Alds + (32 * w + 16) * 32;
    unsigned short* lb0 = Blds + (32 * w) * 32;
    unsigned short* lb1 = Blds + (32 * w + 16) * 32;

    const int wr  = (w >> 1) * 64;
    const int wc  = (w & 1) * 64;
    const int fm  = l & 15;
    const int fkb = (((l >> 4) ^ ((fm & 3) ^ ((fm >> 2) & 3)))) * 16;   // swizzled read

    f32x4 acc[4][4] = {};
    const char* Ab = (const char*)Alds;
    const char* Bb = (const char*)Blds;

    const int nk = K >> 5;
    for (int kt = 0; kt < nk; ++kt) {
        __syncthreads();
        __builtin_amdgcn_global_load_lds((const __attribute__((address_space(1))) void*)ga0,
                                         (__attribute__((address_space(3))) void*)la0, 16, 0, 0);
        __builtin_amdgcn_global_load_lds((const __attribute__((address_space(1))) void*)ga1,
                                         (__attribute__((address_space(3))) void*)la1, 16, 0, 0);
        __builtin_amdgcn_global_load_lds((const __attribute__((address_space(1))) void*)gb0,
                                         (__attribute__((address_space(3))) void*)lb0, 16, 0, 0);
        __builtin_amdgcn_global_load_lds((const __attribute__((address_space(1))) void*)gb1,
                                         (__attribute__((address_space(3))) void*)lb1, 16, 0, 0);
        ga0 += 64; ga1 += 64; gb0 += 64; gb1 += 64;
        __syncthreads();

        bf16x8 af[4], bfr[4];
#pragma unroll
        for (int t = 0; t < 4; ++t) {
            af[t]  = *(const bf16x8*)(Ab + (wr + t * 16 + fm) * 64 + fkb);
            bfr[t] = *(const bf16x8*)(Bb + (wc + t * 16 + fm) * 64 + fkb);
        }
#pragma unroll
        for (int i = 0; i < 4; ++i)
#pragma unroll
            for (int j = 0; j < 4; ++j)
                acc[i][j] = __builtin_amdgcn_mfma_f32_16x16x32_bf16(af[i], bfr[j], acc[i][j], 0, 0, 0);
    }

    // epilogue: C/D layout col = lane&15, row = (lane>>4)*4 + reg
    const float* corr = (const float*)(wsb + OFF_CORR);
    const int ocol = col0 + wc + fm;
    const int rq   = (l >> 4) * 4;
    float bv[4];
#pragma unroll
    for (int j = 0; j < 4; ++j) bv[j] = bias[ocol + j * 16];

#pragma unroll
    for (int i = 0; i < 4; ++i) {
#pragma unroll
        for (int r = 0; r < 4; ++r) {
            const int rr  = row0 + wr + i * 16 + rq + r;
            const int ssl = rr & 255;
            const int bb  = rr >> 8;
            const int ss  = s_lo + ssl;
            float* op = out + ((size_t)(bb * SDIM + ss)) * DDIM + ocol;
            if (!is_tail && ssl < 2) {
                const float* cp = corr + ((size_t)bb * 2 + ssl) * DDIM + ocol;
#pragma unroll
                for (int j = 0; j < 4; ++j)
                    op[j * 16] = acc[i][j][r] + bv[j] + cp[j * 16];
            } else {
#pragma unroll
                for (int j = 0; j < 4; ++j)
                    op[j * 16] = acc[i][j][r] + bv[j];
            }
        }
    }
}

extern "C" void kernel_launch(void* const* d_in, const int* in_sizes, int n_in,
                              void* d_out, int out_size, void* d_ws, size_t ws_size,
                              hipStream_t stream)
{
    const float* X  = (const float*)d_in[0];
    const float* W1 = (const float*)d_in[1];
    const float* b1 = (const float*)d_in[2];
    const float* W2 = (const float*)d_in[3];
    const float* b2 = (const float*)d_in[4];
    const float* W3 = (const float*)d_in[5];
    const float* b3 = (const float*)d_in[6];
    const float* W4 = (const float*)d_in[7];
    const float* b4 = (const float*)d_in[8];
    float* out = (float*)d_out;
    char*  wsb = (char*)d_ws;

    prep_all<<<dim3(PREP_BLOCKS), dim3(256), 0, stream>>>(X, W1, b1, W2, b2, W3, b3, W4, b4, wsb);

    mega<<<dim3(1024), dim3(256), 0, stream>>>(
        (const unsigned short*)(wsb + OFF_XP), wsb, b1, out);
}

// Round 5
// 212.537 us; speedup vs baseline: 1.2249x; 1.2249x over previous
//
#include <hip/hip_runtime.h>
#include <hip/hip_bf16.h>

// B=64, S=512, E=256, D=512
#define EDIM 256
#define SDIM 512
#define BDIM 64
#define DDIM 512
#define SPAD 514   // padded S rows per batch in Xp (2 zero rows at front)

// ws byte offsets
#define OFF_XP    0u           // bf16 [64][514][256]  = 16,842,752 B
#define OFF_GINTB 16842752u    // bf16 [512][1536]     =  1,572,864 B
#define OFF_W1B   18415616u    // bf16 [512][256]      =    262,144 B
#define OFF_CORR  18677760u    // f32  [512][128]      =    262,144 B   (layout [d][b*2+s])
#define OFF_BI    18939904u    // f32  [512]

// prep grid partition
#define CVT_BLOCKS  4112       // 64*514*32 / 256
#define WB_BASE     4112       // + 512 weight blocks
#define CORR_BASE   4624       // + 512 corr blocks (one per d)
#define PREP_BLOCKS 5136

typedef __attribute__((ext_vector_type(8))) __bf16 bf16x8;
typedef __attribute__((ext_vector_type(4))) float  f32x4;
typedef __attribute__((ext_vector_type(8))) unsigned short ushort8v;

__device__ __forceinline__ unsigned short f2bf(float f) {
    unsigned int u = __float_as_uint(f);
    u = (u + 0x7fffu + ((u >> 16) & 1u)) >> 16;   // RNE
    return (unsigned short)u;
}

// ============ launch 1: cvt_pad + weight-combine + edge-correction ============
__global__ __launch_bounds__(256) void prep_all(
    const float* __restrict__ X,
    const float* __restrict__ W1, const float* __restrict__ b1,
    const float* __restrict__ W2, const float* __restrict__ b2,
    const float* __restrict__ W3, const float* __restrict__ b3,
    const float* __restrict__ W4, const float* __restrict__ b4,
    char* __restrict__ wsb)
{
    const int tid = threadIdx.x;

    if (blockIdx.x < CVT_BLOCKS) {
        // ---- bf16 copy of X with 2 zero rows prepended per batch, 8 elem/thread ----
        unsigned short* Xp = (unsigned short*)(wsb + OFF_XP);
        const int i   = blockIdx.x * 256 + tid;    // [0, 64*514*32)
        const int row = i >> 5;                    // b*514 + j
        const int q   = i & 31;                    // 8-elem group
        const int b   = row / SPAD;
        const int j   = row - b * SPAD;
        ushort8v v;
        if (j < 2) {
            v = (ushort8v)0;
        } else {
            const float* src = X + ((size_t)(b * SDIM + j - 2)) * EDIM + q * 8;
            const float4 f0 = *(const float4*)(src);
            const float4 f1 = *(const float4*)(src + 4);
            v[0] = f2bf(f0.x); v[1] = f2bf(f0.y); v[2] = f2bf(f0.z); v[3] = f2bf(f0.w);
            v[4] = f2bf(f1.x); v[5] = f2bf(f1.y); v[6] = f2bf(f1.z); v[7] = f2bf(f1.w);
        }
        *(ushort8v*)(Xp + (size_t)row * EDIM + q * 8) = v;
        return;
    }

    if (blockIdx.x < CORR_BASE) {
        // ---- combined interior weights (delta grouping; see R0 derivation) ----
        const int d = blockIdx.x - WB_BASE;  // 0..511
        const int e = tid;                   // 0..255
        const int de = d * EDIM + e;

        const float w1  = W1[de];
        const float w20 = W2[de * 2 + 0], w21 = W2[de * 2 + 1];
        const float w30 = W3[de * 3 + 0], w31 = W3[de * 3 + 1], w32 = W3[de * 3 + 2];
        const float w40 = W4[de * 4 + 0], w41 = W4[de * 4 + 1], w42 = W4[de * 4 + 2], w43 = W4[de * 4 + 3];

        unsigned short* Gi = (unsigned short*)(wsb + OFF_GINTB) + (size_t)d * 1536;
        Gi[0 * EDIM + e] = f2bf(w40);
        Gi[1 * EDIM + e] = f2bf(w30 + w40 + w41);
        Gi[2 * EDIM + e] = f2bf(w1 + w20 + w30 + w31 + w40 + w41 + w42);
        Gi[3 * EDIM + e] = f2bf(w21 + w31 + w32 + w41 + w42 + w43);
        Gi[4 * EDIM + e] = f2bf(w32 + w42 + w43);
        Gi[5 * EDIM + e] = f2bf(w43);

        ((unsigned short*)(wsb + OFF_W1B))[de] = f2bf(w1);

        if (e == 0)
            ((float*)(wsb + OFF_BI))[d] = b1[d] + b2[d] + 2.0f * b3[d] + 3.0f * b4[d];
        return;
    }

    // ---- edge correction, one block per d (coalesced weight rows):
    //      corr0[b] = -sum_e[x0*(w31+w41+w42) + x1*(w32+w42+w43) + x2*w43] - (b3+2b4)
    //      corr1[b] = -sum_e[x0*w41 + x1*w42 + x2*w43] - b4
    //      stored as corr[d][b*2+s].
    {
        __shared__ float cls[128];
        const int d = blockIdx.x - CORR_BASE;   // 0..511
        const int e = tid;                      // 0..255

        if (tid < 128) cls[tid] = 0.f;

        // per-thread coefficients (row-local, coalesced within the wave)
        const float w31 = W3[(size_t)d * 768 + 3 * e + 1];
        const float w32 = W3[(size_t)d * 768 + 3 * e + 2];
        const float4 w4v = *(const float4*)(W4 + (size_t)d * 1024 + 4 * e);
        const float w41 = w4v.y, w42 = w4v.z, w43 = w4v.w;

        const float c00 = w31 + w41 + w42;   // s=0 coeff of x[b,0,e]
        const float c01 = w32 + w42 + w43;   // s=0 coeff of x[b,1,e]
        const float c02 = w43;               // s=0 coeff of x[b,2,e]
        __syncthreads();

        const float* xb = X + e;
        for (int b = 0; b < BDIM; ++b) {
            const float* xr = xb + (size_t)b * (SDIM * EDIM);
            const float x0 = xr[0], x1 = xr[EDIM], x2 = xr[2 * EDIM];
            float a0 = c00 * x0 + c01 * x1 + c02 * x2;
            float a1 = w41 * x0 + w42 * x1 + w43 * x2;
#pragma unroll
            for (int off = 32; off >= 1; off >>= 1) {
                a0 += __shfl_xor(a0, off, 64);
                a1 += __shfl_xor(a1, off, 64);
            }
            if ((tid & 63) == 0) {
                atomicAdd(&cls[b * 2 + 0], a0);
                atomicAdd(&cls[b * 2 + 1], a1);
            }
        }
        __syncthreads();

        if (tid < 128) {
            const int s = tid & 1;
            const float bc = s ? b4[d] : (b3[d] + 2.f * b4[d]);
            ((float*)(wsb + OFF_CORR))[(size_t)d * 128 + tid] = -cls[tid] - bc;
        }
    }
}

// ============ launch 2: uniform GEMM grid ============
// blocks [0,512):    interior GEMM, s in [0,256), K=1536, + corr on s=0,1
// blocks [512,1024): tail GEMM,     s in [256,512), K=256
// LDS fragment layout uses XOR swizzle sw(r)=(r&3)^((r>>2)&3) on the 16B atom
// index (applied identically at staging-fetch and fragment-read).
__global__ __launch_bounds__(256) void mega(
    const unsigned short* __restrict__ Xp,
    const char* __restrict__ wsb,
    const float* __restrict__ b1,
    float* __restrict__ out)
{
    __shared__ __align__(16) char smem[16384];
    const int id  = blockIdx.x;
    const int tid = threadIdx.x;

    const bool is_tail = id >= 512;
    const int  idx  = is_tail ? id - 512 : id;
    const int  row0 = (idx & 127) * 128;
    const int  col0 = (idx >> 7) * 128;
    const int  K     = is_tail ? 256 : 1536;
    const int  s_lo  = is_tail ? 256 : 0;
    const int  aoff  = is_tail ? 2 : 0;
    const unsigned short* Gbf = is_tail ? (const unsigned short*)(wsb + OFF_W1B)
                                        : (const unsigned short*)(wsb + OFF_GINTB);
    const float* bias = is_tail ? b1 : (const float*)(wsb + OFF_BI);

    unsigned short* Alds = (unsigned short*)smem;             // [128][32]
    unsigned short* Blds = (unsigned short*)(smem + 8192);    // [128][32]

    const int w = tid >> 6;
    const int l = tid & 63;

    // staging: wave w stages chunks {2w,2w+1} of A and B (16 rows x 64 B each)
    const int sub = l >> 2;
    const int kb  = (((l & 3) ^ ((sub & 3) ^ ((sub >> 2) & 3)))) * 16;  // swizzled atom

    const int ra0 = row0 + 32 * w + sub;
    const int ra1 = ra0 + 16;
    const int ba0 = ra0 >> 8, sa0 = ra0 & 255;
    const int ba1 = ra1 >> 8, sa1 = ra1 & 255;
    const char* ga0 = (const char*)(Xp + ((size_t)(ba0 * SPAD + s_lo + sa0 + aoff)) * EDIM) + kb;
    const char* ga1 = (const char*)(Xp + ((size_t)(ba1 * SPAD + s_lo + sa1 + aoff)) * EDIM) + kb;
    const char* gb0 = (const char*)(Gbf + (size_t)(col0 + 32 * w + sub) * K) + kb;
    const char* gb1 = (const char*)(Gbf + (size_t)(col0 + 32 * w + 16 + sub) * K) + kb;

    unsigned short* la0 = Alds + (32 * w) * 32;
    unsigned short* la1 = Alds + (32 * w + 16) * 32;
    unsigned short* lb0 = Blds + (32 * w) * 32;
    unsigned short* lb1 = Blds + (32 * w + 16) * 32;

    const int wr  = (w >> 1) * 64;
    const int wc  = (w & 1) * 64;
    const int fm  = l & 15;
    const int fkb = (((l >> 4) ^ ((fm & 3) ^ ((fm >> 2) & 3)))) * 16;   // swizzled read

    f32x4 acc[4][4] = {};
    const char* Ab = (const char*)Alds;
    const char* Bb = (const char*)Blds;

    const int nk = K >> 5;
    for (int kt = 0; kt < nk; ++kt) {
        __syncthreads();
        __builtin_amdgcn_global_load_lds((const __attribute__((address_space(1))) void*)ga0,
                                         (__attribute__((address_space(3))) void*)la0, 16, 0, 0);
        __builtin_amdgcn_global_load_lds((const __attribute__((address_space(1))) void*)ga1,
                                         (__attribute__((address_space(3))) void*)la1, 16, 0, 0);
        __builtin_amdgcn_global_load_lds((const __attribute__((address_space(1))) void*)gb0,
                                         (__attribute__((address_space(3))) void*)lb0, 16, 0, 0);
        __builtin_amdgcn_global_load_lds((const __attribute__((address_space(1))) void*)gb1,
                                         (__attribute__((address_space(3))) void*)lb1, 16, 0, 0);
        ga0 += 64; ga1 += 64; gb0 += 64; gb1 += 64;
        __syncthreads();

        bf16x8 af[4], bfr[4];
#pragma unroll
        for (int t = 0; t < 4; ++t) {
            af[t]  = *(const bf16x8*)(Ab + (wr + t * 16 + fm) * 64 + fkb);
            bfr[t] = *(const bf16x8*)(Bb + (wc + t * 16 + fm) * 64 + fkb);
        }
#pragma unroll
        for (int i = 0; i < 4; ++i)
#pragma unroll
            for (int j = 0; j < 4; ++j)
                acc[i][j] = __builtin_amdgcn_mfma_f32_16x16x32_bf16(af[i], bfr[j], acc[i][j], 0, 0, 0);
    }

    // epilogue: C/D layout col = lane&15, row = (lane>>4)*4 + reg
    const float* corr = (const float*)(wsb + OFF_CORR);   // [d][b*2+s]
    const int ocol = col0 + wc + fm;
    const int rq   = (l >> 4) * 4;
    float bv[4];
#pragma unroll
    for (int j = 0; j < 4; ++j) bv[j] = bias[ocol + j * 16];

#pragma unroll
    for (int i = 0; i < 4; ++i) {
#pragma unroll
        for (int r = 0; r < 4; ++r) {
            const int rr  = row0 + wr + i * 16 + rq + r;
            const int ssl = rr & 255;
            const int bb  = rr >> 8;
            const int ss  = s_lo + ssl;
            float* op = out + ((size_t)(bb * SDIM + ss)) * DDIM + ocol;
            if (!is_tail && ssl < 2) {
                const float* cp = corr + (size_t)ocol * 128 + bb * 2 + ssl;
#pragma unroll
                for (int j = 0; j < 4; ++j)
                    op[j * 16] = acc[i][j][r] + bv[j] + cp[(size_t)j * 16 * 128];
            } else {
#pragma unroll
                for (int j = 0; j < 4; ++j)
                    op[j * 16] = acc[i][j][r] + bv[j];
            }
        }
    }
}

extern "C" void kernel_launch(void* const* d_in, const int* in_sizes, int n_in,
                              void* d_out, int out_size, void* d_ws, size_t ws_size,
                              hipStream_t stream)
{
    const float* X  = (const float*)d_in[0];
    const float* W1 = (const float*)d_in[1];
    const float* b1 = (const float*)d_in[2];
    const float* W2 = (const float*)d_in[3];
    const float* b2 = (const float*)d_in[4];
    const float* W3 = (const float*)d_in[5];
    const float* b3 = (const float*)d_in[6];
    const float* W4 = (const float*)d_in[7];
    const float* b4 = (const float*)d_in[8];
    float* out = (float*)d_out;
    char*  wsb = (char*)d_ws;

    prep_all<<<dim3(PREP_BLOCKS), dim3(256), 0, stream>>>(X, W1, b1, W2, b2, W3, b3, W4, b4, wsb);

    mega<<<dim3(1024), dim3(256), 0, stream>>>(
        (const unsigned short*)(wsb + OFF_XP), wsb, b1, out);
}

// Round 6
// 165.219 us; speedup vs baseline: 1.5757x; 1.2864x over previous
//
#include <hip/hip_runtime.h>
#include <hip/hip_bf16.h>

// B=64, S=512, E=256, D=512
#define EDIM 256
#define SDIM 512
#define BDIM 64
#define DDIM 512
#define SPAD 514   // padded S rows per batch in Xp (2 zero rows at front)

// ws byte offsets
#define OFF_XP    0u           // bf16 [64][514][256]  = 16,842,752 B
#define OFF_GINTB 16842752u    // bf16 [512][1536]     =  1,572,864 B
#define OFF_W1B   18415616u    // bf16 [512][256]      =    262,144 B
#define OFF_CORR  18677760u    // f32  [512][128]      =    262,144 B   (layout [d][b*2+s])
#define OFF_BI    18939904u    // f32  [512]

// prep grid partition
#define CVT_BLOCKS  4112       // 64*514*32 / 256
#define WB_BASE     4112       // + 512 weight blocks
#define CORR_BASE   4624       // + 4096 corr blocks (512 d x 8 b-chunks)
#define PREP_BLOCKS 8720

typedef __attribute__((ext_vector_type(8))) __bf16 bf16x8;
typedef __attribute__((ext_vector_type(4))) float  f32x4;
typedef __attribute__((ext_vector_type(8))) unsigned short ushort8v;

__device__ __forceinline__ unsigned short f2bf(float f) {
    unsigned int u = __float_as_uint(f);
    u = (u + 0x7fffu + ((u >> 16) & 1u)) >> 16;   // RNE
    return (unsigned short)u;
}

// ============ launch 1: cvt_pad + weight-combine + edge-correction ============
__global__ __launch_bounds__(256) void prep_all(
    const float* __restrict__ X,
    const float* __restrict__ W1, const float* __restrict__ b1,
    const float* __restrict__ W2, const float* __restrict__ b2,
    const float* __restrict__ W3, const float* __restrict__ b3,
    const float* __restrict__ W4, const float* __restrict__ b4,
    char* __restrict__ wsb)
{
    const int tid = threadIdx.x;

    if (blockIdx.x < CVT_BLOCKS) {
        // ---- bf16 copy of X with 2 zero rows prepended per batch, 8 elem/thread ----
        unsigned short* Xp = (unsigned short*)(wsb + OFF_XP);
        const int i   = blockIdx.x * 256 + tid;    // [0, 64*514*32)
        const int row = i >> 5;                    // b*514 + j
        const int q   = i & 31;                    // 8-elem group
        const int b   = row / SPAD;
        const int j   = row - b * SPAD;
        ushort8v v;
        if (j < 2) {
            v = (ushort8v)0;
        } else {
            const float* src = X + ((size_t)(b * SDIM + j - 2)) * EDIM + q * 8;
            const float4 f0 = *(const float4*)(src);
            const float4 f1 = *(const float4*)(src + 4);
            v[0] = f2bf(f0.x); v[1] = f2bf(f0.y); v[2] = f2bf(f0.z); v[3] = f2bf(f0.w);
            v[4] = f2bf(f1.x); v[5] = f2bf(f1.y); v[6] = f2bf(f1.z); v[7] = f2bf(f1.w);
        }
        *(ushort8v*)(Xp + (size_t)row * EDIM + q * 8) = v;
        return;
    }

    if (blockIdx.x < CORR_BASE) {
        // ---- combined interior weights (delta grouping; see R0 derivation) ----
        const int d = blockIdx.x - WB_BASE;  // 0..511
        const int e = tid;                   // 0..255
        const int de = d * EDIM + e;

        const float w1  = W1[de];
        const float w20 = W2[de * 2 + 0], w21 = W2[de * 2 + 1];
        const float w30 = W3[de * 3 + 0], w31 = W3[de * 3 + 1], w32 = W3[de * 3 + 2];
        const float w40 = W4[de * 4 + 0], w41 = W4[de * 4 + 1], w42 = W4[de * 4 + 2], w43 = W4[de * 4 + 3];

        unsigned short* Gi = (unsigned short*)(wsb + OFF_GINTB) + (size_t)d * 1536;
        Gi[0 * EDIM + e] = f2bf(w40);
        Gi[1 * EDIM + e] = f2bf(w30 + w40 + w41);
        Gi[2 * EDIM + e] = f2bf(w1 + w20 + w30 + w31 + w40 + w41 + w42);
        Gi[3 * EDIM + e] = f2bf(w21 + w31 + w32 + w41 + w42 + w43);
        Gi[4 * EDIM + e] = f2bf(w32 + w42 + w43);
        Gi[5 * EDIM + e] = f2bf(w43);

        ((unsigned short*)(wsb + OFF_W1B))[de] = f2bf(w1);

        if (e == 0)
            ((float*)(wsb + OFF_BI))[d] = b1[d] + b2[d] + 2.0f * b3[d] + 3.0f * b4[d];
        return;
    }

    // ---- edge correction, block = (d, 8-batch chunk); coalesced weight rows.
    //      corr0[b] = -sum_e[x0*(w31+w41+w42) + x1*(w32+w42+w43) + x2*w43] - (b3+2b4)
    //      corr1[b] = -sum_e[x0*w41 + x1*w42 + x2*w43] - b4
    //      stored as corr[d][b*2+s].
    {
        __shared__ float cls[16];
        const int cb = blockIdx.x - CORR_BASE;   // 0..4095
        const int d  = cb >> 3;                  // 0..511
        const int bq = (cb & 7) * 8;             // batch chunk base
        const int e  = tid;                      // 0..255

        if (tid < 16) cls[tid] = 0.f;

        const float w31 = W3[(size_t)d * 768 + 3 * e + 1];
        const float w32 = W3[(size_t)d * 768 + 3 * e + 2];
        const float4 w4v = *(const float4*)(W4 + (size_t)d * 1024 + 4 * e);
        const float w41 = w4v.y, w42 = w4v.z, w43 = w4v.w;

        const float c00 = w31 + w41 + w42;
        const float c01 = w32 + w42 + w43;
        const float c02 = w43;
        __syncthreads();

#pragma unroll
        for (int bi = 0; bi < 8; ++bi) {
            const float* xr = X + (size_t)(bq + bi) * (SDIM * EDIM) + e;
            const float x0 = xr[0], x1 = xr[EDIM], x2 = xr[2 * EDIM];
            float a0 = c00 * x0 + c01 * x1 + c02 * x2;
            float a1 = w41 * x0 + w42 * x1 + w43 * x2;
#pragma unroll
            for (int off = 32; off >= 1; off >>= 1) {
                a0 += __shfl_xor(a0, off, 64);
                a1 += __shfl_xor(a1, off, 64);
            }
            if ((tid & 63) == 0) {
                atomicAdd(&cls[bi * 2 + 0], a0);
                atomicAdd(&cls[bi * 2 + 1], a1);
            }
        }
        __syncthreads();

        if (tid < 16) {
            const int s = tid & 1;
            const float bc = s ? b4[d] : (b3[d] + 2.f * b4[d]);
            ((float*)(wsb + OFF_CORR))[(size_t)d * 128 + bq * 2 + tid] = -cls[tid] - bc;
        }
    }
}

// ============ launch 2: uniform GEMM grid (R3 structure, no swizzle) ============
// blocks [0,512):    interior GEMM, s in [0,256), K=1536, + corr on s=0,1
// blocks [512,1024): tail GEMM,     s in [256,512), K=256
__global__ __launch_bounds__(256) void mega(
    const unsigned short* __restrict__ Xp,
    const char* __restrict__ wsb,
    const float* __restrict__ b1,
    float* __restrict__ out)
{
    __shared__ __align__(16) char smem[16384];
    const int id  = blockIdx.x;
    const int tid = threadIdx.x;

    const bool is_tail = id >= 512;
    const int  idx  = is_tail ? id - 512 : id;
    const int  row0 = (idx & 127) * 128;
    const int  col0 = (idx >> 7) * 128;
    const int  K     = is_tail ? 256 : 1536;
    const int  s_lo  = is_tail ? 256 : 0;
    const int  aoff  = is_tail ? 2 : 0;
    const unsigned short* Gbf = is_tail ? (const unsigned short*)(wsb + OFF_W1B)
                                        : (const unsigned short*)(wsb + OFF_GINTB);
    const float* bias = is_tail ? b1 : (const float*)(wsb + OFF_BI);

    unsigned short* Alds = (unsigned short*)smem;             // [128][32]
    unsigned short* Blds = (unsigned short*)(smem + 8192);    // [128][32]

    const int w = tid >> 6;
    const int l = tid & 63;

    // staging: wave w stages chunks {2w,2w+1} of A and B (16 rows x 64 B each)
    const int sub = l >> 2;
    const int kb  = (l & 3) * 16;

    const int ra0 = row0 + 32 * w + sub;
    const int ra1 = ra0 + 16;
    const int ba0 = ra0 >> 8, sa0 = ra0 & 255;
    const int ba1 = ra1 >> 8, sa1 = ra1 & 255;
    const char* ga0 = (const char*)(Xp + ((size_t)(ba0 * SPAD + s_lo + sa0 + aoff)) * EDIM) + kb;
    const char* ga1 = (const char*)(Xp + ((size_t)(ba1 * SPAD + s_lo + sa1 + aoff)) * EDIM) + kb;
    const char* gb0 = (const char*)(Gbf + (size_t)(col0 + 32 * w + sub) * K) + kb;
    const char* gb1 = (const char*)(Gbf + (size_t)(col0 + 32 * w + 16 + sub) * K) + kb;

    unsigned short* la0 = Alds + (32 * w) * 32;
    unsigned short* la1 = Alds + (32 * w + 16) * 32;
    unsigned short* lb0 = Blds + (32 * w) * 32;
    unsigned short* lb1 = Blds + (32 * w + 16) * 32;

    const int wr  = (w >> 1) * 64;
    const int wc  = (w & 1) * 64;
    const int fm  = l & 15;
    const int fkb = (l >> 4) * 16;

    f32x4 acc[4][4] = {};
    const char* Ab = (const char*)Alds;
    const char* Bb = (const char*)Blds;

    const int nk = K >> 5;
    for (int kt = 0; kt < nk; ++kt) {
        __syncthreads();
        __builtin_amdgcn_global_load_lds((const __attribute__((address_space(1))) void*)ga0,
                                         (__attribute__((address_space(3))) void*)la0, 16, 0, 0);
        __builtin_amdgcn_global_load_lds((const __attribute__((address_space(1))) void*)ga1,
                                         (__attribute__((address_space(3))) void*)la1, 16, 0, 0);
        __builtin_amdgcn_global_load_lds((const __attribute__((address_space(1))) void*)gb0,
                                         (__attribute__((address_space(3))) void*)lb0, 16, 0, 0);
        __builtin_amdgcn_global_load_lds((const __attribute__((address_space(1))) void*)gb1,
                                         (__attribute__((address_space(3))) void*)lb1, 16, 0, 0);
        ga0 += 64; ga1 += 64; gb0 += 64; gb1 += 64;
        __syncthreads();

        bf16x8 af[4], bfr[4];
#pragma unroll
        for (int t = 0; t < 4; ++t) {
            af[t]  = *(const bf16x8*)(Ab + (wr + t * 16 + fm) * 64 + fkb);
            bfr[t] = *(const bf16x8*)(Bb + (wc + t * 16 + fm) * 64 + fkb);
        }
#pragma unroll
        for (int i = 0; i < 4; ++i)
#pragma unroll
            for (int j = 0; j < 4; ++j)
                acc[i][j] = __builtin_amdgcn_mfma_f32_16x16x32_bf16(af[i], bfr[j], acc[i][j], 0, 0, 0);
    }

    // epilogue: C/D layout col = lane&15, row = (lane>>4)*4 + reg
    const float* corr = (const float*)(wsb + OFF_CORR);   // [d][b*2+s]
    const int ocol = col0 + wc + fm;
    const int rq   = (l >> 4) * 4;
    float bv[4];
#pragma unroll
    for (int j = 0; j < 4; ++j) bv[j] = bias[ocol + j * 16];

#pragma unroll
    for (int i = 0; i < 4; ++i) {
#pragma unroll
        for (int r = 0; r < 4; ++r) {
            const int rr  = row0 + wr + i * 16 + rq + r;
            const int ssl = rr & 255;
            const int bb  = rr >> 8;
            const int ss  = s_lo + ssl;
            float* op = out + ((size_t)(bb * SDIM + ss)) * DDIM + ocol;
            if (!is_tail && ssl < 2) {
                const float* cp = corr + (size_t)ocol * 128 + bb * 2 + ssl;
#pragma unroll
                for (int j = 0; j < 4; ++j)
                    op[j * 16] = acc[i][j][r] + bv[j] + cp[(size_t)j * 16 * 128];
            } else {
#pragma unroll
                for (int j = 0; j < 4; ++j)
                    op[j * 16] = acc[i][j][r] + bv[j];
            }
        }
    }
}

extern "C" void kernel_launch(void* const* d_in, const int* in_sizes, int n_in,
                              void* d_out, int out_size, void* d_ws, size_t ws_size,
                              hipStream_t stream)
{
    const float* X  = (const float*)d_in[0];
    const float* W1 = (const float*)d_in[1];
    const float* b1 = (const float*)d_in[2];
    const float* W2 = (const float*)d_in[3];
    const float* b2 = (const float*)d_in[4];
    const float* W3 = (const float*)d_in[5];
    const float* b3 = (const float*)d_in[6];
    const float* W4 = (const float*)d_in[7];
    const float* b4 = (const float*)d_in[8];
    float* out = (float*)d_out;
    char*  wsb = (char*)d_ws;

    prep_all<<<dim3(PREP_BLOCKS), dim3(256), 0, stream>>>(X, W1, b1, W2, b2, W3, b3, W4, b4, wsb);

    mega<<<dim3(1024), dim3(256), 0, stream>>>(
        (const unsigned short*)(wsb + OFF_XP), wsb, b1, out);
}